// Round 1
// baseline (33.865 us; speedup 1.0000x reference)
//
#include <hip/hip_runtime.h>
#include <math.h>

#define LL 500
#define BB 4
#define EE 100000
#define NBINS 24

struct f3 { float x, y, z; };

__device__ __forceinline__ f3 ld3(const float* __restrict__ p) {
    f3 r; r.x = p[0]; r.y = p[1]; r.z = p[2]; return r;
}
__device__ __forceinline__ f3 sub3(f3 a, f3 b) {
    f3 r; r.x = a.x - b.x; r.y = a.y - b.y; r.z = a.z - b.z; return r;
}
__device__ __forceinline__ f3 cross3(f3 a, f3 b) {
    f3 r;
    r.x = a.y * b.z - a.z * b.y;
    r.y = a.z * b.x - a.x * b.z;
    r.z = a.x * b.y - a.y * b.x;
    return r;
}
__device__ __forceinline__ float dot3(f3 a, f3 b) {
    return fmaf(a.x, b.x, fmaf(a.y, b.y, a.z * b.z));
}

__global__ void __launch_bounds__(256) theta_restraint_kernel(
    const float* __restrict__ N,
    const float* __restrict__ CA,
    const float* __restrict__ CB,
    const float* __restrict__ coeff,
    const int* __restrict__ x_idx,
    const int* __restrict__ y_idx,
    float* __restrict__ out)
{
    const int i = blockIdx.x * blockDim.x + threadIdx.x;
    float val = 0.0f;
    if (i < BB * EE) {
        const int e = i >> 2;       // edge index
        const int b = i & 3;        // batch index (adjacent lanes share edge)
        const int x = x_idx[e];
        const int y = y_idx[e];

        const float* Nb  = N  + b * (LL * 3);
        const float* CAb = CA + b * (LL * 3);
        const float* CBb = CB + b * (LL * 3);

        const f3 xN  = ld3(Nb  + 3 * x);
        const f3 xCA = ld3(CAb + 3 * x);
        const f3 xCB = ld3(CBb + 3 * x);
        const f3 yCB = ld3(CBb + 3 * y);

        const f3 b1 = sub3(xCA, xN);
        const f3 b2 = sub3(xCB, xCA);
        const f3 b3 = sub3(yCB, xCB);

        const f3 n1 = cross3(b1, b2);
        const f3 n2 = cross3(b2, b3);

        // m = cross(n1, b2/||b2||); dot(m,n2) = dot(cross(n1,b2),n2) / ||b2||
        const float rn = rsqrtf(dot3(b2, b2));
        const f3 m = cross3(n1, b2);
        const float s = dot3(m, n2) * rn;
        const float c = dot3(n1, n2);

        const float theta = atan2f(s, c);

        const float step  = 0.261799387799149436f;      // 15 * pi / 180
        const float c0    = -3.14159265358979324f + 0.5f * step;
        const float twoPi = 6.28318530717958648f;

        const float tw = (theta < c0) ? theta + twoPi : theta;

        int seg = (int)floorf((tw - c0) / step);
        seg = seg < 0 ? 0 : (seg > NBINS - 1 ? NBINS - 1 : seg);

        const float t = tw - (c0 + (float)seg * step);

        const float4 cs = *reinterpret_cast<const float4*>(
            coeff + (((size_t)x * LL + (size_t)y) * NBINS + (size_t)seg) * 4);

        val = fmaf(fmaf(fmaf(cs.w, t, cs.z), t, cs.y), t, cs.x);
    }

    // wave64 reduction
    #pragma unroll
    for (int off = 32; off > 0; off >>= 1)
        val += __shfl_down(val, off, 64);

    __shared__ float wsum[4];
    const int lane = threadIdx.x & 63;
    const int wid  = threadIdx.x >> 6;
    if (lane == 0) wsum[wid] = val;
    __syncthreads();
    if (threadIdx.x == 0) {
        atomicAdd(out, wsum[0] + wsum[1] + wsum[2] + wsum[3]);
    }
}

extern "C" void kernel_launch(void* const* d_in, const int* in_sizes, int n_in,
                              void* d_out, int out_size, void* d_ws, size_t ws_size,
                              hipStream_t stream) {
    const float* N     = (const float*)d_in[0];
    const float* CA    = (const float*)d_in[1];
    const float* CB    = (const float*)d_in[2];
    const float* coeff = (const float*)d_in[3];
    const int* x_idx   = (const int*)d_in[4];
    const int* y_idx   = (const int*)d_in[5];
    float* out = (float*)d_out;

    hipMemsetAsync(out, 0, sizeof(float), stream);

    const int total = BB * EE;
    const int block = 256;
    const int grid = (total + block - 1) / block;
    theta_restraint_kernel<<<grid, block, 0, stream>>>(N, CA, CB, coeff,
                                                       x_idx, y_idx, out);
}

// Round 2
// 15.843 us; speedup vs baseline: 2.1376x; 2.1376x over previous
//
#include <hip/hip_runtime.h>
#include <math.h>

#define LL 500
#define BB 4
#define EE 100000
#define NBINS 24
#define TOTAL (BB * EE)
#define BLOCK 256
#define GRID ((TOTAL + BLOCK - 1) / BLOCK)   // 1563

struct f3 { float x, y, z; };

__device__ __forceinline__ f3 ld3(const float* __restrict__ p) {
    f3 r; r.x = p[0]; r.y = p[1]; r.z = p[2]; return r;
}
__device__ __forceinline__ f3 sub3(f3 a, f3 b) {
    f3 r; r.x = a.x - b.x; r.y = a.y - b.y; r.z = a.z - b.z; return r;
}
__device__ __forceinline__ f3 cross3(f3 a, f3 b) {
    f3 r;
    r.x = a.y * b.z - a.z * b.y;
    r.y = a.z * b.x - a.x * b.z;
    r.z = a.x * b.y - a.y * b.x;
    return r;
}
__device__ __forceinline__ float dot3(f3 a, f3 b) {
    return fmaf(a.x, b.x, fmaf(a.y, b.y, a.z * b.z));
}

__global__ void __launch_bounds__(BLOCK) theta_partial_kernel(
    const float* __restrict__ N,
    const float* __restrict__ CA,
    const float* __restrict__ CB,
    const float* __restrict__ coeff,
    const int* __restrict__ x_idx,
    const int* __restrict__ y_idx,
    float* __restrict__ partials)
{
    const int i = blockIdx.x * BLOCK + threadIdx.x;
    float val = 0.0f;
    if (i < TOTAL) {
        const int e = i >> 2;       // edge index
        const int b = i & 3;        // batch index (adjacent lanes share edge)
        const int x = x_idx[e];
        const int y = y_idx[e];

        const float* Nb  = N  + b * (LL * 3);
        const float* CAb = CA + b * (LL * 3);
        const float* CBb = CB + b * (LL * 3);

        const f3 xN  = ld3(Nb  + 3 * x);
        const f3 xCA = ld3(CAb + 3 * x);
        const f3 xCB = ld3(CBb + 3 * x);
        const f3 yCB = ld3(CBb + 3 * y);

        const f3 b1 = sub3(xCA, xN);
        const f3 b2 = sub3(xCB, xCA);
        const f3 b3 = sub3(yCB, xCB);

        const f3 n1 = cross3(b1, b2);
        const f3 n2 = cross3(b2, b3);

        // dot(cross(n1, b2u), n2) = dot(cross(n1,b2), n2) / ||b2||
        const float rn = rsqrtf(dot3(b2, b2));
        const f3 m = cross3(n1, b2);
        const float s = dot3(m, n2) * rn;
        const float c = dot3(n1, n2);

        const float theta = atan2f(s, c);

        const float step  = 0.261799387799149436f;      // 15 * pi / 180
        const float c0    = -3.14159265358979324f + 0.5f * step;
        const float twoPi = 6.28318530717958648f;

        const float tw = (theta < c0) ? theta + twoPi : theta;

        int seg = (int)floorf((tw - c0) / step);
        seg = seg < 0 ? 0 : (seg > NBINS - 1 ? NBINS - 1 : seg);

        const float t = tw - (c0 + (float)seg * step);

        const float4 cs = *reinterpret_cast<const float4*>(
            coeff + (((size_t)x * LL + (size_t)y) * NBINS + (size_t)seg) * 4);

        val = fmaf(fmaf(fmaf(cs.w, t, cs.z), t, cs.y), t, cs.x);
    }

    // wave64 reduction
    #pragma unroll
    for (int off = 32; off > 0; off >>= 1)
        val += __shfl_down(val, off, 64);

    __shared__ float wsum[BLOCK / 64];
    const int lane = threadIdx.x & 63;
    const int wid  = threadIdx.x >> 6;
    if (lane == 0) wsum[wid] = val;
    __syncthreads();
    if (threadIdx.x == 0) {
        partials[blockIdx.x] = wsum[0] + wsum[1] + wsum[2] + wsum[3];
    }
}

__global__ void __launch_bounds__(BLOCK) theta_reduce_kernel(
    const float* __restrict__ partials,
    float* __restrict__ out)
{
    float v = 0.0f;
    for (int i = threadIdx.x; i < GRID; i += BLOCK)
        v += partials[i];

    #pragma unroll
    for (int off = 32; off > 0; off >>= 1)
        v += __shfl_down(v, off, 64);

    __shared__ float wsum[BLOCK / 64];
    const int lane = threadIdx.x & 63;
    const int wid  = threadIdx.x >> 6;
    if (lane == 0) wsum[wid] = v;
    __syncthreads();
    if (threadIdx.x == 0) {
        out[0] = wsum[0] + wsum[1] + wsum[2] + wsum[3];
    }
}

extern "C" void kernel_launch(void* const* d_in, const int* in_sizes, int n_in,
                              void* d_out, int out_size, void* d_ws, size_t ws_size,
                              hipStream_t stream) {
    const float* N     = (const float*)d_in[0];
    const float* CA    = (const float*)d_in[1];
    const float* CB    = (const float*)d_in[2];
    const float* coeff = (const float*)d_in[3];
    const int* x_idx   = (const int*)d_in[4];
    const int* y_idx   = (const int*)d_in[5];
    float* out      = (float*)d_out;
    float* partials = (float*)d_ws;   // GRID floats, overwritten every call

    theta_partial_kernel<<<GRID, BLOCK, 0, stream>>>(N, CA, CB, coeff,
                                                     x_idx, y_idx, partials);
    theta_reduce_kernel<<<1, BLOCK, 0, stream>>>(partials, out);
}